// Round 4
// baseline (366.588 us; speedup 1.0000x reference)
//
#include <hip/hip_runtime.h>
#include <hip/hip_bf16.h>
#include <stdint.h>

typedef __bf16 bf16x8 __attribute__((ext_vector_type(8)));
typedef float  f32x4  __attribute__((ext_vector_type(4)));
typedef unsigned int u32x4 __attribute__((ext_vector_type(4)));
typedef unsigned short u16;
typedef unsigned int   u32;

#define B_  32
#define N_  128
#define F_  128
#define G_  300
#define GP  320   // G padded to multiple of 32
#define NTILE 36  // upper-triangle 16x16 tile-pairs
#define TILE_E 32768  // elements per tile: 16*16*128

__device__ __forceinline__ float b2f(u16 v){
  union { u32 u; float f; } x; x.u = ((u32)v) << 16; return x.f;
}
__device__ __forceinline__ u16 f2b(float f){
  union { float f; u32 u; } x; x.f = f;
  u32 r = x.u + 0x7FFFu + ((x.u >> 16) & 1u);
  return (u16)(r >> 16);
}
// pack 2 f32 -> 2 bf16 (round-half-up) in one u32: lo=a, hi=b
__device__ __forceinline__ u32 pk2(float a, float b){
  return __builtin_amdgcn_perm(__float_as_uint(b) + 0x8000u,
                               __float_as_uint(a) + 0x8000u, 0x07060302u);
}
// shifted softplus: ln2*(log2(1+2^(x*log2e)) - 1)
__device__ __forceinline__ float sspf(float x){
  return fmaf(0.69314718f, __log2f(1.0f + __builtin_amdgcn_exp2f(1.44269504f*x)),
              -0.69314718f);
}
__device__ __forceinline__ f32x4 mfma16(bf16x8 a, bf16x8 b, f32x4 c){
  return __builtin_amdgcn_mfma_f32_16x16x32_bf16(a, b, c, 0, 0, 0);
}

// ---------------- setup: transpose+cast weight matrices to bf16 ----------------
__global__ __launch_bounds__(256) void k_setup(const float* __restrict__ w_f1,
                                               const float* __restrict__ w_f2,
                                               const float* __restrict__ w_in2f,
                                               u16* __restrict__ w1t,
                                               u16* __restrict__ w2t,
                                               u16* __restrict__ wi2t){
  int idx = blockIdx.x*256 + threadIdx.x;
  if (idx < 128*GP){
    int k = idx / GP, g = idx % GP;
    w1t[idx] = (g < G_) ? f2b(w_f1[g*F_ + k]) : (u16)0;
  } else if (idx < 128*GP + 128*128){
    int j = idx - 128*GP; int h = j / 128, k = j % 128;
    w2t[h*128 + k] = f2b(w_f2[k*128 + h]);
  } else if (idx < 128*GP + 2*128*128){
    int j = idx - 128*GP - 128*128; int h = j / 128, ff = j % 128;
    wi2t[h*128 + ff] = f2b(w_in2f[ff*128 + h]);
  }
}

// ---------------- x = emb[z] (fp32) ----------------
__global__ __launch_bounds__(256) void k_embed(const int* __restrict__ z,
                                               const float* __restrict__ emb,
                                               float* __restrict__ x){
  int idx = blockIdx.x*256 + threadIdx.x;   // < 32*128*128
  int bn = idx >> 7, ff = idx & 127;
  x[idx] = emb[z[bn]*F_ + ff];
}

// ---------------- filter network, register-chained, upper-triangle compact W ----
// block = (bl, tile-pair(ti<=tj), half): 8 i-rows x 16 j x 128 h.
// GEMM1 computed as W1^T (A=w1t rows f, B=rbf rows pair) so C-layout chains into
// b64 LDS writes + b128 A2-fragment reads. w1t/w2t read direct from global (L2-hot).
__global__ __launch_bounds__(256, 3) void k_filter(const float* __restrict__ r,
                                                   const u16* __restrict__ w1t,
                                                   const u16* __restrict__ w2t,
                                                   const float* __restrict__ bf1,
                                                   const float* __restrict__ bf2,
                                                   u16* __restrict__ W,
                                                   int b0){
  __shared__ __attribute__((aligned(16))) u16 w1s[128*128];  // [p][f] XOR-even swizzled; reused for C2
  __shared__ float dsh[128];

  int tid = threadIdx.x, lane = tid & 63, wave = tid >> 6;
  int m = lane & 15, q = lane >> 4;

  int idx  = blockIdx.x;
  int half = idx & 1;
  int rem  = idx >> 1;
  int Tt   = rem % NTILE;
  int bl   = rem / NTILE;
  int b    = b0 + bl;
  int ti = 0;
  { int cnt = 8;
    while (Tt >= cnt){ Tt -= cnt; cnt--; ti++; } }
  int tj = ti + Tt;

  const float KS = 3.79828256f;              // sqrt(10*log2(e))
  const float KC = KS * (30.0f/299.0f);
  if (tid < 128){
    const float* rb = r + (size_t)(b*N_)*3;
    int ii = ti*16 + half*8 + (tid >> 4), jj = tj*16 + (tid & 15);
    float dx = rb[ii*3]   - rb[jj*3];
    float dy = rb[ii*3+1] - rb[jj*3+1];
    float dz = rb[ii*3+2] - rb[jj*3+2];
    dsh[tid] = KS * sqrtf(dx*dx + dy*dy + dz*dz + 1e-12f);
  }
  __syncthreads();

  int rows0 = wave*32;                       // wave owns pairs [rows0, rows0+32)
  float sd0 = dsh[rows0 + m];
  float sd1 = dsh[rows0 + 16 + m];
  const float nkc2 = -KC*KC;
  const float tkc  = 2.0f*KC;
  const float srat = __builtin_amdgcn_exp2f(-2.0f*KC*KC);

  f32x4 acc1[8][2];
  #pragma unroll
  for (int ni = 0; ni < 8; ++ni){ acc1[ni][0] = (f32x4){0,0,0,0}; acc1[ni][1] = (f32x4){0,0,0,0}; }

  // ---- GEMM1: W1^T = w1t * rbf^T, K = 320, A from global (L2), B in-register ----
  int vb = m*GP + q*8;
  bf16x8 a1c[8], a1n[8];
  #pragma unroll
  for (int ni = 0; ni < 8; ++ni)
    a1c[ni] = *reinterpret_cast<const bf16x8*>(w1t + vb + ni*16*GP);
  for (int ks = 0; ks < 10; ++ks){
    if (ks < 9){
      #pragma unroll
      for (int ni = 0; ni < 8; ++ni)
        a1n[ni] = *reinterpret_cast<const bf16x8*>(w1t + vb + ni*16*GP + (ks+1)*32);
    }
    float sct0 = KC * (float)(ks*32 + q*8);
    bf16x8 b1f[2];
    #pragma unroll
    for (int mi = 0; mi < 2; ++mi){
      float sd = mi ? sd1 : sd0;
      float t0 = sd - sct0;
      float fv0 = __builtin_amdgcn_exp2f(-(t0*t0));
      float rr_ = __builtin_amdgcn_exp2f(fmaf(tkc, t0, nkc2));
      float fv[8];
      fv[0] = fv0;
      #pragma unroll
      for (int t = 1; t < 8; ++t){ fv0 = fv0*rr_; rr_ = rr_*srat; fv[t] = fv0; }
      u32x4 au;
      #pragma unroll
      for (int t2 = 0; t2 < 4; ++t2) au[t2] = pk2(fv[t2*2], fv[t2*2+1]);
      b1f[mi] = __builtin_bit_cast(bf16x8, au);
    }
    #pragma unroll
    for (int ni = 0; ni < 8; ++ni){
      acc1[ni][0] = mfma16(a1c[ni], b1f[0], acc1[ni][0]);
      acc1[ni][1] = mfma16(a1c[ni], b1f[1], acc1[ni][1]);
    }
    #pragma unroll
    for (int ni = 0; ni < 8; ++ni) a1c[ni] = a1n[ni];
  }

  // ---- epilogue 1: +b_f1, ssp, pack -> w1s[p][f] (b64 writes, XOR-even) ----
  #pragma unroll
  for (int ni = 0; ni < 8; ++ni){
    float4 bia = *reinterpret_cast<const float4*>(bf1 + ni*16 + q*4);
    #pragma unroll
    for (int mi = 0; mi < 2; ++mi){
      int p = rows0 + mi*16 + m;
      u32 x0 = pk2(sspf(acc1[ni][mi][0] + bia.x), sspf(acc1[ni][mi][1] + bia.y));
      u32 x1 = pk2(sspf(acc1[ni][mi][2] + bia.z), sspf(acc1[ni][mi][3] + bia.w));
      int phys = (ni*4 + q) ^ (p & 30);
      *reinterpret_cast<uint2*>(&w1s[p*128 + phys*4]) = make_uint2(x0, x1);
    }
  }
  __syncthreads();

  // ---- GEMM2: W = W1 @ w_f2 (A=W1 from LDS b128, B=w2t from global) ----
  f32x4 acc2[8][2];
  #pragma unroll
  for (int ni = 0; ni < 8; ++ni){ acc2[ni][0] = (f32x4){0,0,0,0}; acc2[ni][1] = (f32x4){0,0,0,0}; }
  #pragma unroll
  for (int ks2 = 0; ks2 < 4; ++ks2){
    bf16x8 a2[2];
    #pragma unroll
    for (int mi = 0; mi < 2; ++mi){
      int p = rows0 + mi*16 + m;
      int phys = (ks2*8 + q*2) ^ (p & 30);
      a2[mi] = *reinterpret_cast<const bf16x8*>(&w1s[p*128 + phys*4]);
    }
    #pragma unroll
    for (int ni2 = 0; ni2 < 8; ++ni2){
      bf16x8 b2 = *reinterpret_cast<const bf16x8*>(w2t + (ni2*16 + m)*128 + ks2*32 + q*8);
      acc2[ni2][0] = mfma16(a2[0], b2, acc2[ni2][0]);
      acc2[ni2][1] = mfma16(a2[1], b2, acc2[ni2][1]);
    }
  }
  __syncthreads();   // w1s reads done; reuse as C2 buffer

  // ---- epilogue 2: +b_f2 -> w1s[p][h] (bf16, XOR-even) ----
  #pragma unroll
  for (int ni2 = 0; ni2 < 8; ++ni2){
    float bb = bf2[ni2*16 + m];
    #pragma unroll
    for (int mi = 0; mi < 2; ++mi)
      #pragma unroll
      for (int rr = 0; rr < 4; ++rr){
        int p = rows0 + mi*16 + q*4 + rr;
        int phys = (ni2*4 + (m >> 2)) ^ (p & 30);
        w1s[p*128 + phys*4 + (m & 3)] = f2b(acc2[ni2][mi][rr] + bb);
      }
  }
  __syncthreads();

  // ---- dense contiguous store into compact tile (no mirror) ----
  int tIdx = ti*8 - (ti*(ti-1))/2 + (tj - ti);
  u16* Wt = W + ((size_t)bl*NTILE + tIdx)*TILE_E + half*16384;
  #pragma unroll
  for (int v = 0; v < 8; ++v){
    int o = v*2048 + tid*8;          // u16 offset in 16K half-tile
    int p = o >> 7;
    int g8 = (o & 127) >> 2;         // even
    int phys = g8 ^ (p & 30);
    bf16x8 val = *reinterpret_cast<const bf16x8*>(&w1s[p*128 + phys*4]);
    *reinterpret_cast<bf16x8*>(Wt + o) = val;
  }
}

// ---------------- f = x @ w_in2f (fp32 out), one block per b ----------------
__global__ __launch_bounds__(256) void k_inlin(const float* __restrict__ x,
                                               const u16* __restrict__ wi2t,
                                               float* __restrict__ f,
                                               int b0){
  __shared__ __attribute__((aligned(16))) u16 xa[128][136];
  __shared__ __attribute__((aligned(16))) u16 wb[128][136];
  int b = b0 + blockIdx.x;
  int tid = threadIdx.x, lane = tid & 63, wave = tid >> 6;
  int m = lane & 15, q = lane >> 4;
  {
    int row = tid >> 1, half = (tid & 1)*64;
    const float* src = x + ((size_t)b*N_ + row)*F_ + half;
    #pragma unroll
    for (int v = 0; v < 16; ++v){
      float4 t = *reinterpret_cast<const float4*>(src + v*4);
      xa[row][half + v*4]     = f2b(t.x);
      xa[row][half + v*4 + 1] = f2b(t.y);
      xa[row][half + v*4 + 2] = f2b(t.z);
      xa[row][half + v*4 + 3] = f2b(t.w);
    }
    const u16* s2 = wi2t + row*128 + half;
    #pragma unroll
    for (int v = 0; v < 8; ++v)
      *reinterpret_cast<bf16x8*>(&wb[row][half + v*8]) = *reinterpret_cast<const bf16x8*>(s2 + v*8);
  }
  __syncthreads();
  int jr = (wave >> 1)*64, kc = (wave & 1)*64;
  f32x4 acc[4][4];
  #pragma unroll
  for (int mi = 0; mi < 4; ++mi)
    #pragma unroll
    for (int ni = 0; ni < 4; ++ni) acc[mi][ni] = (f32x4){0.f,0.f,0.f,0.f};
  #pragma unroll
  for (int ks = 0; ks < 4; ++ks){
    int k0 = ks*32;
    bf16x8 af[4], bf[4];
    #pragma unroll
    for (int mi = 0; mi < 4; ++mi)
      af[mi] = *reinterpret_cast<const bf16x8*>(&xa[jr + mi*16 + m][k0 + q*8]);
    #pragma unroll
    for (int ni = 0; ni < 4; ++ni)
      bf[ni] = *reinterpret_cast<const bf16x8*>(&wb[kc + ni*16 + m][k0 + q*8]);
    #pragma unroll
    for (int mi = 0; mi < 4; ++mi)
      #pragma unroll
      for (int ni = 0; ni < 4; ++ni)
        acc[mi][ni] = mfma16(af[mi], bf[ni], acc[mi][ni]);
  }
  float* fp = f + (size_t)b*N_*F_;
  #pragma unroll
  for (int mi = 0; mi < 4; ++mi)
    #pragma unroll
    for (int ni = 0; ni < 4; ++ni)
      #pragma unroll
      for (int rr = 0; rr < 4; ++rr)
        fp[(jr + mi*16 + q*4 + rr)*F_ + kc + ni*16 + m] = acc[mi][ni][rr];
}

// ------- cfconv + atom-wise MLP + residual; block = (b, 16-row i-tile) -------
// reads compact upper-triangle tiles (transposed access for tj < ti)
__global__ __launch_bounds__(256) void k_interact(const float* __restrict__ f,
                                                  const u16* __restrict__ W,
                                                  const float* __restrict__ w_f2out,
                                                  const float* __restrict__ b_f2out,
                                                  const float* __restrict__ w_out,
                                                  const float* __restrict__ b_out,
                                                  float* __restrict__ x,
                                                  int b0){
  __shared__ __attribute__((aligned(16))) float fsh[128][132];
  __shared__ float ysh[16][132];
  int bl = blockIdx.x >> 3, ti = blockIdx.x & 7;
  int b  = b0 + bl;
  int tid = threadIdx.x;
  int il = tid >> 4, hq = tid & 15, h0 = hq*8;
  {
    int row = tid >> 1, half = (tid & 1)*64;
    const float* src = f + ((size_t)b*N_ + row)*F_ + half;
    #pragma unroll
    for (int v = 0; v < 16; ++v)
      *reinterpret_cast<float4*>(&fsh[row][half + v*4]) = *reinterpret_cast<const float4*>(src + v*4);
  }
  __syncthreads();

  // cfconv: y[i,h] = sum_j W[b,i,j,h] * f[b,j,h]
  float y[8] = {0,0,0,0,0,0,0,0};
  const u16* Wb = W + (size_t)bl*NTILE*TILE_E;
  for (int tjj = 0; tjj < 8; ++tjj){
    const u16* Wt; int bse, str;
    if (tjj >= ti){
      Wt = Wb + ((size_t)(ti*8 - (ti*(ti-1))/2 + tjj - ti))*TILE_E;
      bse = il*2048; str = 128;
    } else {
      Wt = Wb + ((size_t)(tjj*8 - (tjj*(tjj-1))/2 + ti - tjj))*TILE_E;
      bse = il*128;  str = 2048;
    }
    const u16* wp = Wt + bse + h0;
    const float* frow = &fsh[tjj*16][0];
    #pragma unroll 4
    for (int jl = 0; jl < 16; ++jl){
      bf16x8 wv = *reinterpret_cast<const bf16x8*>(wp + jl*str);
      float4 fa = *reinterpret_cast<const float4*>(frow + jl*132 + h0);
      float4 fb = *reinterpret_cast<const float4*>(frow + jl*132 + h0 + 4);
      y[0] += (float)wv[0]*fa.x; y[1] += (float)wv[1]*fa.y;
      y[2] += (float)wv[2]*fa.z; y[3] += (float)wv[3]*fa.w;
      y[4] += (float)wv[4]*fb.x; y[5] += (float)wv[5]*fb.y;
      y[6] += (float)wv[6]*fb.z; y[7] += (float)wv[7]*fb.w;
    }
  }
  #pragma unroll
  for (int t = 0; t < 8; ++t) ysh[il][h0 + t] = y[t];
  __syncthreads();

  // y2 = ssp(y @ w_f2out + b_f2out)   (fp32 weights, exact)
  float y2[8] = {0,0,0,0,0,0,0,0};
  for (int k = 0; k < 128; ++k){
    float yv = ysh[il][k];
    float4 wa = *reinterpret_cast<const float4*>(w_f2out + k*F_ + h0);
    float4 wb = *reinterpret_cast<const float4*>(w_f2out + k*F_ + h0 + 4);
    y2[0] += yv*wa.x; y2[1] += yv*wa.y; y2[2] += yv*wa.z; y2[3] += yv*wa.w;
    y2[4] += yv*wb.x; y2[5] += yv*wb.y; y2[6] += yv*wb.z; y2[7] += yv*wb.w;
  }
  #pragma unroll
  for (int t = 0; t < 8; ++t) y2[t] = sspf(y2[t] + b_f2out[h0 + t]);
  __syncthreads();
  #pragma unroll
  for (int t = 0; t < 8; ++t) ysh[il][h0 + t] = y2[t];
  __syncthreads();

  // v = y2 @ w_out + b_out ; x += v
  float v2[8] = {0,0,0,0,0,0,0,0};
  for (int k = 0; k < 128; ++k){
    float yv = ysh[il][k];
    float4 wa = *reinterpret_cast<const float4*>(w_out + k*F_ + h0);
    float4 wb = *reinterpret_cast<const float4*>(w_out + k*F_ + h0 + 4);
    v2[0] += yv*wa.x; v2[1] += yv*wa.y; v2[2] += yv*wa.z; v2[3] += yv*wa.w;
    v2[4] += yv*wb.x; v2[5] += yv*wb.y; v2[6] += yv*wb.z; v2[7] += yv*wb.w;
  }
  float* xp = x + ((size_t)b*N_ + ti*16 + il)*F_ + h0;
  #pragma unroll
  for (int t = 0; t < 8; ++t) xp[t] = xp[t] + v2[t] + b_out[h0 + t];
}

// ---------------- readout: out = ssp(x@w_aw1+b)@w_aw2 + b2 ----------------
__global__ __launch_bounds__(256) void k_readout(const float* __restrict__ x,
                                                 const float* __restrict__ w_aw1,
                                                 const float* __restrict__ b_aw1,
                                                 const float* __restrict__ w_aw2,
                                                 const float* __restrict__ b_aw2,
                                                 float* __restrict__ out){
  int tid = threadIdx.x, lane = tid & 63, wave = tid >> 6;
  int atom = blockIdx.x*4 + wave;           // < 4096
  const float* xr = x + (size_t)atom*F_;
  float a0 = 0.f, a1 = 0.f;
  int f0 = lane, f1 = lane + 64;
  for (int k = 0; k < 128; ++k){
    float xv = xr[k];
    a0 += xv*w_aw1[k*F_ + f0];
    a1 += xv*w_aw1[k*F_ + f1];
  }
  float h0 = sspf(a0 + b_aw1[f0]);
  float h1 = sspf(a1 + b_aw1[f1]);
  float s = h0*w_aw2[f0] + h1*w_aw2[f1];
  #pragma unroll
  for (int off = 32; off; off >>= 1) s += __shfl_down(s, off, 64);
  if (lane == 0) out[atom] = s + b_aw2[0];
}

extern "C" void kernel_launch(void* const* d_in, const int* in_sizes, int n_in,
                              void* d_out, int out_size, void* d_ws, size_t ws_size,
                              hipStream_t stream){
  const int*   z       = (const int*)d_in[0];
  const float* r       = (const float*)d_in[1];
  const float* emb     = (const float*)d_in[2];
  const float* w_in2f  = (const float*)d_in[3];
  const float* w_f1    = (const float*)d_in[4];
  const float* b_f1    = (const float*)d_in[5];
  const float* w_f2    = (const float*)d_in[6];
  const float* b_f2    = (const float*)d_in[7];
  const float* w_f2out = (const float*)d_in[8];
  const float* b_f2out = (const float*)d_in[9];
  const float* w_out   = (const float*)d_in[10];
  const float* b_out   = (const float*)d_in[11];
  const float* w_aw1   = (const float*)d_in[12];
  const float* b_aw1   = (const float*)d_in[13];
  const float* w_aw2   = (const float*)d_in[14];
  const float* b_aw2   = (const float*)d_in[15];

  // workspace layout: small fixed region first, compact W (chunked over b) after
  char* ws = (char*)d_ws;
  float* x    = (float*)(ws);                        // 2,097,152 B
  float* f    = (float*)(ws + 2097152);              // 2,097,152 B
  u16*   w1t  = (u16*)(ws + 4194304);                //    81,920 B
  u16*   w2t  = (u16*)(ws + 4276224);                //    32,768 B
  u16*   wi2t = (u16*)(ws + 4308992);                //    32,768 B
  const size_t SMALL_END = 4341760;
  u16*   W    = (u16*)(ws + SMALL_END);
  const size_t WB = (size_t)NTILE*TILE_E*2;          // 2,359,296 B per batch elem

  int chunk_b = 1;
  if (ws_size > SMALL_END + WB){
    size_t cb = (ws_size - SMALL_END) / WB;
    if (cb >= 32)      chunk_b = 32;
    else if (cb >= 16) chunk_b = 16;
    else               chunk_b = (int)cb;
  }

  k_setup<<<288, 256, 0, stream>>>(w_f1, w_f2, w_in2f, w1t, w2t, wi2t);
  k_embed<<<2048, 256, 0, stream>>>(z, emb, x);
  for (int b0 = 0; b0 < B_; b0 += chunk_b){
    int cb = (B_ - b0 < chunk_b) ? (B_ - b0) : chunk_b;
    k_filter<<<cb*NTILE*2, 256, 0, stream>>>(r, w1t, w2t, b_f1, b_f2, W, b0);
    for (int it = 0; it < 3; ++it){
      k_inlin<<<cb, 256, 0, stream>>>(x, wi2t, f, b0);
      k_interact<<<cb*8, 256, 0, stream>>>(f, W, w_f2out, b_f2out, w_out, b_out, x, b0);
    }
  }
  k_readout<<<1024, 256, 0, stream>>>(x, w_aw1, b_aw1, w_aw2, b_aw2, (float*)d_out);
}

// Round 6
// 349.529 us; speedup vs baseline: 1.0488x; 1.0488x over previous
//
#include <hip/hip_runtime.h>
#include <hip/hip_bf16.h>
#include <stdint.h>

typedef __bf16 bf16x8 __attribute__((ext_vector_type(8)));
typedef float  f32x4  __attribute__((ext_vector_type(4)));
typedef unsigned int u32x4 __attribute__((ext_vector_type(4)));
typedef unsigned short u16;
typedef unsigned int   u32;

#define B_  32
#define N_  128
#define F_  128
#define G_  300
#define GP  320   // G padded to multiple of 32
#define NTILE 36  // upper-triangle 16x16 tile-pairs
#define TILE_E 32768  // elements per tile: 16*16*128

__device__ __forceinline__ float b2f(u16 v){
  union { u32 u; float f; } x; x.u = ((u32)v) << 16; return x.f;
}
__device__ __forceinline__ u16 f2b(float f){
  union { float f; u32 u; } x; x.f = f;
  u32 r = x.u + 0x7FFFu + ((x.u >> 16) & 1u);
  return (u16)(r >> 16);
}
// pack 2 f32 -> 2 bf16 (round-half-up) in one u32: lo=a, hi=b
__device__ __forceinline__ u32 pk2(float a, float b){
  return __builtin_amdgcn_perm(__float_as_uint(b) + 0x8000u,
                               __float_as_uint(a) + 0x8000u, 0x07060302u);
}
// shifted softplus: ln2*(log2(1+2^(x*log2e)) - 1)
__device__ __forceinline__ float sspf(float x){
  return fmaf(0.69314718f, __log2f(1.0f + __builtin_amdgcn_exp2f(1.44269504f*x)),
              -0.69314718f);
}
__device__ __forceinline__ f32x4 mfma16(bf16x8 a, bf16x8 b, f32x4 c){
  return __builtin_amdgcn_mfma_f32_16x16x32_bf16(a, b, c, 0, 0, 0);
}

// ---------------- setup: transpose+cast weight matrices to bf16 ----------------
__global__ __launch_bounds__(256) void k_setup(const float* __restrict__ w_f1,
                                               const float* __restrict__ w_f2,
                                               const float* __restrict__ w_in2f,
                                               u16* __restrict__ w1t,
                                               u16* __restrict__ w2t,
                                               u16* __restrict__ wi2t){
  int idx = blockIdx.x*256 + threadIdx.x;
  if (idx < 128*GP){
    int k = idx / GP, g = idx % GP;
    w1t[idx] = (g < G_) ? f2b(w_f1[g*F_ + k]) : (u16)0;
  } else if (idx < 128*GP + 128*128){
    int j = idx - 128*GP; int h = j / 128, k = j % 128;
    w2t[h*128 + k] = f2b(w_f2[k*128 + h]);
  } else if (idx < 128*GP + 2*128*128){
    int j = idx - 128*GP - 128*128; int h = j / 128, ff = j % 128;
    wi2t[h*128 + ff] = f2b(w_in2f[ff*128 + h]);
  }
}

// ---------------- x = emb[z] (fp32) ----------------
__global__ __launch_bounds__(256) void k_embed(const int* __restrict__ z,
                                               const float* __restrict__ emb,
                                               float* __restrict__ x){
  int idx = blockIdx.x*256 + threadIdx.x;   // < 32*128*128
  int bn = idx >> 7, ff = idx & 127;
  x[idx] = emb[z[bn]*F_ + ff];
}

// ---------------- filter network, compact upper-triangle W ----------------
// block = (bl, tile-pair(ti<=tj), half): 8 i-rows x 16 j x 128 h.
// nt stores keep weights L2-resident; per-block [dmin,dmax] skips dead gaussians.
__global__ __launch_bounds__(256, 3) void k_filter(const float* __restrict__ r,
                                                   const u16* __restrict__ w1t,
                                                   const u16* __restrict__ w2t,
                                                   const float* __restrict__ bf1,
                                                   const float* __restrict__ bf2,
                                                   u16* __restrict__ W,
                                                   int b0){
  __shared__ __attribute__((aligned(16))) u16 w1s[128*128];  // [p][f] XOR-even; reused for C2
  __shared__ float dsh[128];
  __shared__ float mnmx[2];

  int tid = threadIdx.x, lane = tid & 63, wave = tid >> 6;
  int m = lane & 15, q = lane >> 4;

  int idx  = blockIdx.x;
  int half = idx & 1;
  int rem  = idx >> 1;
  int Tt   = rem % NTILE;
  int bl   = rem / NTILE;
  int b    = b0 + bl;
  int ti = 0;
  { int cnt = 8;
    while (Tt >= cnt){ Tt -= cnt; cnt--; ti++; } }
  int tj = ti + Tt;

  const float KS = 3.79828256f;              // sqrt(10*log2(e))
  const float KC = KS * (30.0f/299.0f);
  if (tid < 128){
    const float* rb = r + (size_t)(b*N_)*3;
    int ii = ti*16 + half*8 + (tid >> 4), jj = tj*16 + (tid & 15);
    float dx = rb[ii*3]   - rb[jj*3];
    float dy = rb[ii*3+1] - rb[jj*3+1];
    float dz = rb[ii*3+2] - rb[jj*3+2];
    dsh[tid] = KS * sqrtf(dx*dx + dy*dy + dz*dz + 1e-12f);
  }
  __syncthreads();
  if (tid < 64){
    float v0 = dsh[tid], v1 = dsh[tid + 64];
    float mn = fminf(v0, v1), mx = fmaxf(v0, v1);
    #pragma unroll
    for (int off = 32; off; off >>= 1){
      mn = fminf(mn, __shfl_xor(mn, off, 64));
      mx = fmaxf(mx, __shfl_xor(mx, off, 64));
    }
    if (tid == 0){ mnmx[0] = mn; mnmx[1] = mx; }
  }
  __syncthreads();
  // active gaussian chunk range: centers within ~1.25 Angstrom of [dmin,dmax]
  int ks0 = (int)floorf((mnmx[0] - 4.75f) / (32.0f*KC));
  int ks1 = (int)floorf((mnmx[1] + 4.75f) / (32.0f*KC));
  ks0 = ks0 < 0 ? 0 : ks0;  ks1 = ks1 > 9 ? 9 : ks1;

  int rows0 = wave*32;                       // wave owns pairs [rows0, rows0+32)
  float sd0 = dsh[rows0 + m];
  float sd1 = dsh[rows0 + 16 + m];
  const float nkc2 = -KC*KC;
  const float tkc  = 2.0f*KC;
  const float srat = __builtin_amdgcn_exp2f(-2.0f*KC*KC);

  f32x4 acc1[8][2];
  #pragma unroll
  for (int ni = 0; ni < 8; ++ni){ acc1[ni][0] = (f32x4){0,0,0,0}; acc1[ni][1] = (f32x4){0,0,0,0}; }

  // ---- GEMM1: W1^T = w1t * rbf^T, K in [ks0*32, ks1*32+32) ----
  int vb = m*GP + q*8;
  bf16x8 a1c[8], a1n[8];
  #pragma unroll
  for (int ni = 0; ni < 8; ++ni)
    a1c[ni] = *reinterpret_cast<const bf16x8*>(w1t + vb + ni*16*GP + ks0*32);
  for (int ks = ks0; ks <= ks1; ++ks){
    if (ks < ks1){
      #pragma unroll
      for (int ni = 0; ni < 8; ++ni)
        a1n[ni] = *reinterpret_cast<const bf16x8*>(w1t + vb + ni*16*GP + (ks+1)*32);
    }
    float sct0 = KC * (float)(ks*32 + q*8);
    bf16x8 b1f[2];
    #pragma unroll
    for (int mi = 0; mi < 2; ++mi){
      float sd = mi ? sd1 : sd0;
      float t0 = sd - sct0;
      float fv0 = __builtin_amdgcn_exp2f(-(t0*t0));
      float rr_ = __builtin_amdgcn_exp2f(fmaf(tkc, t0, nkc2));
      float fv[8];
      fv[0] = fv0;
      #pragma unroll
      for (int t = 1; t < 8; ++t){ fv0 = fv0*rr_; rr_ = rr_*srat; fv[t] = fv0; }
      u32x4 au;
      #pragma unroll
      for (int t2 = 0; t2 < 4; ++t2) au[t2] = pk2(fv[t2*2], fv[t2*2+1]);
      b1f[mi] = __builtin_bit_cast(bf16x8, au);
    }
    #pragma unroll
    for (int ni = 0; ni < 8; ++ni){
      acc1[ni][0] = mfma16(a1c[ni], b1f[0], acc1[ni][0]);
      acc1[ni][1] = mfma16(a1c[ni], b1f[1], acc1[ni][1]);
    }
    #pragma unroll
    for (int ni = 0; ni < 8; ++ni) a1c[ni] = a1n[ni];
  }

  // ---- epilogue 1: +b_f1, ssp, pack -> w1s[p][f] (b64 writes, XOR-even) ----
  #pragma unroll
  for (int ni = 0; ni < 8; ++ni){
    float4 bia = *reinterpret_cast<const float4*>(bf1 + ni*16 + q*4);
    #pragma unroll
    for (int mi = 0; mi < 2; ++mi){
      int p = rows0 + mi*16 + m;
      u32 x0 = pk2(sspf(acc1[ni][mi][0] + bia.x), sspf(acc1[ni][mi][1] + bia.y));
      u32 x1 = pk2(sspf(acc1[ni][mi][2] + bia.z), sspf(acc1[ni][mi][3] + bia.w));
      int phys = (ni*4 + q) ^ (p & 30);
      *reinterpret_cast<uint2*>(&w1s[p*128 + phys*4]) = make_uint2(x0, x1);
    }
  }
  __syncthreads();

  // ---- GEMM2: W = W1 @ w_f2 (A=W1 from LDS b128, B=w2t from global L2) ----
  f32x4 acc2[8][2];
  #pragma unroll
  for (int ni = 0; ni < 8; ++ni){ acc2[ni][0] = (f32x4){0,0,0,0}; acc2[ni][1] = (f32x4){0,0,0,0}; }
  #pragma unroll
  for (int ks2 = 0; ks2 < 4; ++ks2){
    bf16x8 a2[2];
    #pragma unroll
    for (int mi = 0; mi < 2; ++mi){
      int p = rows0 + mi*16 + m;
      int phys = (ks2*8 + q*2) ^ (p & 30);
      a2[mi] = *reinterpret_cast<const bf16x8*>(&w1s[p*128 + phys*4]);
    }
    #pragma unroll
    for (int ni2 = 0; ni2 < 8; ++ni2){
      bf16x8 b2 = *reinterpret_cast<const bf16x8*>(w2t + (ni2*16 + m)*128 + ks2*32 + q*8);
      acc2[ni2][0] = mfma16(a2[0], b2, acc2[ni2][0]);
      acc2[ni2][1] = mfma16(a2[1], b2, acc2[ni2][1]);
    }
  }
  __syncthreads();   // w1s reads done; reuse as C2 buffer

  // ---- epilogue 2: +b_f2 -> w1s[p][h] (bf16, XOR-even) ----
  #pragma unroll
  for (int ni2 = 0; ni2 < 8; ++ni2){
    float bb = bf2[ni2*16 + m];
    #pragma unroll
    for (int mi = 0; mi < 2; ++mi)
      #pragma unroll
      for (int rr = 0; rr < 4; ++rr){
        int p = rows0 + mi*16 + q*4 + rr;
        int phys = (ni2*4 + (m >> 2)) ^ (p & 30);
        w1s[p*128 + phys*4 + (m & 3)] = f2b(acc2[ni2][mi][rr] + bb);
      }
  }
  __syncthreads();

  // ---- dense contiguous nt store into compact tile (no L2 allocate) ----
  int tIdx = ti*8 - (ti*(ti-1))/2 + (tj - ti);
  u16* Wt = W + ((size_t)bl*NTILE + tIdx)*TILE_E + half*16384;
  #pragma unroll
  for (int v = 0; v < 8; ++v){
    int o = v*2048 + tid*8;          // u16 offset in 16K half-tile
    int p = o >> 7;
    int g8 = (o & 127) >> 2;         // even
    int phys = g8 ^ (p & 30);
    u32x4 val = *reinterpret_cast<const u32x4*>(&w1s[p*128 + phys*4]);
    __builtin_nontemporal_store(val, reinterpret_cast<u32x4*>(Wt + o));
  }
}

// ---------------- f = x @ w_in2f (fp32 out), one block per b ----------------
__global__ __launch_bounds__(256) void k_inlin(const float* __restrict__ x,
                                               const u16* __restrict__ wi2t,
                                               float* __restrict__ f,
                                               int b0){
  __shared__ __attribute__((aligned(16))) u16 xa[128][136];
  __shared__ __attribute__((aligned(16))) u16 wb[128][136];
  int b = b0 + blockIdx.x;
  int tid = threadIdx.x, lane = tid & 63, wave = tid >> 6;
  int m = lane & 15, q = lane >> 4;
  {
    int row = tid >> 1, half = (tid & 1)*64;
    const float* src = x + ((size_t)b*N_ + row)*F_ + half;
    #pragma unroll
    for (int v = 0; v < 16; ++v){
      float4 t = *reinterpret_cast<const float4*>(src + v*4);
      xa[row][half + v*4]     = f2b(t.x);
      xa[row][half + v*4 + 1] = f2b(t.y);
      xa[row][half + v*4 + 2] = f2b(t.z);
      xa[row][half + v*4 + 3] = f2b(t.w);
    }
    const u16* s2 = wi2t + row*128 + half;
    #pragma unroll
    for (int v = 0; v < 8; ++v)
      *reinterpret_cast<bf16x8*>(&wb[row][half + v*8]) = *reinterpret_cast<const bf16x8*>(s2 + v*8);
  }
  __syncthreads();
  int jr = (wave >> 1)*64, kc = (wave & 1)*64;
  f32x4 acc[4][4];
  #pragma unroll
  for (int mi = 0; mi < 4; ++mi)
    #pragma unroll
    for (int ni = 0; ni < 4; ++ni) acc[mi][ni] = (f32x4){0.f,0.f,0.f,0.f};
  #pragma unroll
  for (int ks = 0; ks < 4; ++ks){
    int k0 = ks*32;
    bf16x8 af[4], bf[4];
    #pragma unroll
    for (int mi = 0; mi < 4; ++mi)
      af[mi] = *reinterpret_cast<const bf16x8*>(&xa[jr + mi*16 + m][k0 + q*8]);
    #pragma unroll
    for (int ni = 0; ni < 4; ++ni)
      bf[ni] = *reinterpret_cast<const bf16x8*>(&wb[kc + ni*16 + m][k0 + q*8]);
    #pragma unroll
    for (int mi = 0; mi < 4; ++mi)
      #pragma unroll
      for (int ni = 0; ni < 4; ++ni)
        acc[mi][ni] = mfma16(af[mi], bf[ni], acc[mi][ni]);
  }
  float* fp = f + (size_t)b*N_*F_;
  #pragma unroll
  for (int mi = 0; mi < 4; ++mi)
    #pragma unroll
    for (int ni = 0; ni < 4; ++ni)
      #pragma unroll
      for (int rr = 0; rr < 4; ++rr)
        fp[(jr + mi*16 + q*4 + rr)*F_ + kc + ni*16 + m] = acc[mi][ni][rr];
}

// ------- cfconv: one block per compact tile; y_i in regs, y_j via per-wave LDS ------
// writes deterministic 8-slot partials yp[bl][slot][row][h]
__global__ __launch_bounds__(256, 3) void k_cfconv(const float* __restrict__ f,
                                                   const u16* __restrict__ W,
                                                   float* __restrict__ yp,
                                                   int b0){
  __shared__ __attribute__((aligned(16))) float fA[16][132];
  __shared__ __attribute__((aligned(16))) float fB[16][132];
  __shared__ __attribute__((aligned(16))) float yjs[4][16][136];

  int tid = threadIdx.x;
  int Tt = blockIdx.x % NTILE, bl = blockIdx.x / NTILE;
  int b = b0 + bl;
  int ti = 0;
  { int cnt = 8;
    while (Tt >= cnt){ Tt -= cnt; cnt--; ti++; } }
  int tj = ti + Tt;
  bool diag = (ti == tj);

  { // stage f tiles: fA = rows ti*16.., fB = rows tj*16..
    int tile = tid >> 7, tl = tid & 127;
    int row = tl >> 3, c0 = (tl & 7)*16;
    int base = (tile ? tj : ti)*16;
    const float* src = f + ((size_t)b*N_ + base + row)*F_ + c0;
    float* dst = tile ? &fB[row][c0] : &fA[row][c0];
    #pragma unroll
    for (int v = 0; v < 4; ++v)
      *reinterpret_cast<float4*>(dst + v*4) = *reinterpret_cast<const float4*>(src + v*4);
  }
  if (!diag){ // zero yjs
    #pragma unroll
    for (int i = 0; i < 34; ++i){
      int o = tid + i*256;
      if (o < 4*16*136) ((float*)yjs)[o] = 0.f;
    }
  }
  __syncthreads();

  int il = tid >> 4, hq = tid & 15, h0 = hq*8, wv = tid >> 6;
  int tIdx = ti*8 - (ti*(ti-1))/2 + (tj - ti);
  const u16* Wt = W + ((size_t)bl*NTILE + tIdx)*TILE_E;

  float yi[8] = {0,0,0,0,0,0,0,0};
  if (diag){
    #pragma unroll 4
    for (int s = 0; s < 16; ++s){
      u32x4 wu = __builtin_nontemporal_load(
        reinterpret_cast<const u32x4*>(Wt + (il*16 + s)*128 + h0));
      bf16x8 w8 = __builtin_bit_cast(bf16x8, wu);
      float4 fa = *reinterpret_cast<const float4*>(&fB[s][h0]);
      float4 fb = *reinterpret_cast<const float4*>(&fB[s][h0 + 4]);
      yi[0] += (float)w8[0]*fa.x; yi[1] += (float)w8[1]*fa.y;
      yi[2] += (float)w8[2]*fa.z; yi[3] += (float)w8[3]*fa.w;
      yi[4] += (float)w8[4]*fb.x; yi[5] += (float)w8[5]*fb.y;
      yi[6] += (float)w8[6]*fb.z; yi[7] += (float)w8[7]*fb.w;
    }
  } else {
    float4 fav = *reinterpret_cast<const float4*>(&fA[il][h0]);
    float4 fbv = *reinterpret_cast<const float4*>(&fA[il][h0 + 4]);
    #pragma unroll 2
    for (int s = 0; s < 16; ++s){
      int jl = (s + il) & 15;
      u32x4 wu = __builtin_nontemporal_load(
        reinterpret_cast<const u32x4*>(Wt + (il*16 + jl)*128 + h0));
      bf16x8 w8 = __builtin_bit_cast(bf16x8, wu);
      float wf[8];
      #pragma unroll
      for (int k = 0; k < 8; ++k) wf[k] = (float)w8[k];
      float4 ga = *reinterpret_cast<const float4*>(&fB[jl][h0]);
      float4 gb = *reinterpret_cast<const float4*>(&fB[jl][h0 + 4]);
      yi[0] += wf[0]*ga.x; yi[1] += wf[1]*ga.y;
      yi[2] += wf[2]*ga.z; yi[3] += wf[3]*ga.w;
      yi[4] += wf[4]*gb.x; yi[5] += wf[5]*gb.y;
      yi[6] += wf[6]*gb.z; yi[7] += wf[7]*gb.w;
      // y_j contribution: row jl gains W[il,jl,:]*fA[il,:], staggered => no intra-wave collision
      float4 p0 = *reinterpret_cast<float4*>(&yjs[wv][jl][h0]);
      float4 p1 = *reinterpret_cast<float4*>(&yjs[wv][jl][h0 + 4]);
      p0.x += wf[0]*fav.x; p0.y += wf[1]*fav.y; p0.z += wf[2]*fav.z; p0.w += wf[3]*fav.w;
      p1.x += wf[4]*fbv.x; p1.y += wf[5]*fbv.y; p1.z += wf[6]*fbv.z; p1.w += wf[7]*fbv.w;
      *reinterpret_cast<float4*>(&yjs[wv][jl][h0])     = p0;
      *reinterpret_cast<float4*>(&yjs[wv][jl][h0 + 4]) = p1;
    }
  }

  // write y_i partial: slot tj, rows ti*16+il
  float* dst = yp + (((size_t)bl*8 + tj)*128 + ti*16 + il)*128 + h0;
  *reinterpret_cast<float4*>(dst)     = make_float4(yi[0], yi[1], yi[2], yi[3]);
  *reinterpret_cast<float4*>(dst + 4) = make_float4(yi[4], yi[5], yi[6], yi[7]);

  if (!diag){
    __syncthreads();
    // reduce 4 wave-partials, write slot ti, rows tj*16+il (thread t: row il, cols h0)
    float4 s0 = make_float4(0,0,0,0), s1 = make_float4(0,0,0,0);
    #pragma unroll
    for (int w = 0; w < 4; ++w){
      float4 a = *reinterpret_cast<const float4*>(&yjs[w][il][h0]);
      float4 c = *reinterpret_cast<const float4*>(&yjs[w][il][h0 + 4]);
      s0.x += a.x; s0.y += a.y; s0.z += a.z; s0.w += a.w;
      s1.x += c.x; s1.y += c.y; s1.z += c.z; s1.w += c.w;
    }
    float* dst2 = yp + (((size_t)bl*8 + ti)*128 + tj*16 + il)*128 + h0;
    *reinterpret_cast<float4*>(dst2)     = s0;
    *reinterpret_cast<float4*>(dst2 + 4) = s1;
  }
}

// ------- mlp: reduce 8 slots -> y; y2=ssp(y@w_f2out+b); v=y2@w_out+b; x+=v -------
__global__ __launch_bounds__(256) void k_mlp(const float* __restrict__ yp,
                                             const float* __restrict__ w_f2out,
                                             const float* __restrict__ b_f2out,
                                             const float* __restrict__ w_out,
                                             const float* __restrict__ b_out,
                                             float* __restrict__ x,
                                             int b0){
  __shared__ float ysh[16][132];
  int bl = blockIdx.x >> 3, R = blockIdx.x & 7;
  int b  = b0 + bl;
  int tid = threadIdx.x;
  int il = tid >> 4, hq = tid & 15, h0 = hq*8;

  float y[8] = {0,0,0,0,0,0,0,0};
  #pragma unroll
  for (int s = 0; s < 8; ++s){
    const float* src = yp + (((size_t)bl*8 + s)*128 + R*16 + il)*128 + h0;
    float4 a = *reinterpret_cast<const float4*>(src);
    float4 c = *reinterpret_cast<const float4*>(src + 4);
    y[0] += a.x; y[1] += a.y; y[2] += a.z; y[3] += a.w;
    y[4] += c.x; y[5] += c.y; y[6] += c.z; y[7] += c.w;
  }
  #pragma unroll
  for (int t = 0; t < 8; ++t) ysh[il][h0 + t] = y[t];
  __syncthreads();

  float y2[8] = {0,0,0,0,0,0,0,0};
  for (int k = 0; k < 128; ++k){
    float yv = ysh[il][k];
    float4 wa = *reinterpret_cast<const float4*>(w_f2out + k*F_ + h0);
    float4 wb = *reinterpret_cast<const float4*>(w_f2out + k*F_ + h0 + 4);
    y2[0] += yv*wa.x; y2[1] += yv*wa.y; y2[2] += yv*wa.z; y2[3] += yv*wa.w;
    y2[4] += yv*wb.x; y2[5] += yv*wb.y; y2[6] += yv*wb.z; y2[7] += yv*wb.w;
  }
  #pragma unroll
  for (int t = 0; t < 8; ++t) y2[t] = sspf(y2[t] + b_f2out[h0 + t]);
  __syncthreads();
  #pragma unroll
  for (int t = 0; t < 8; ++t) ysh[il][h0 + t] = y2[t];
  __syncthreads();

  float v2[8] = {0,0,0,0,0,0,0,0};
  for (int k = 0; k < 128; ++k){
    float yv = ysh[il][k];
    float4 wa = *reinterpret_cast<const float4*>(w_out + k*F_ + h0);
    float4 wb = *reinterpret_cast<const float4*>(w_out + k*F_ + h0 + 4);
    v2[0] += yv*wa.x; v2[1] += yv*wa.y; v2[2] += yv*wa.z; v2[3] += yv*wa.w;
    v2[4] += yv*wb.x; v2[5] += yv*wb.y; v2[6] += yv*wb.z; v2[7] += yv*wb.w;
  }
  float* xp = x + ((size_t)b*N_ + R*16 + il)*F_ + h0;
  #pragma unroll
  for (int t = 0; t < 8; ++t) xp[t] = xp[t] + v2[t] + b_out[h0 + t];
}

// ---------------- readout: out = ssp(x@w_aw1+b)@w_aw2 + b2 ----------------
__global__ __launch_bounds__(256) void k_readout(const float* __restrict__ x,
                                                 const float* __restrict__ w_aw1,
                                                 const float* __restrict__ b_aw1,
                                                 const float* __restrict__ w_aw2,
                                                 const float* __restrict__ b_aw2,
                                                 float* __restrict__ out){
  int tid = threadIdx.x, lane = tid & 63, wave = tid >> 6;
  int atom = blockIdx.x*4 + wave;           // < 4096
  const float* xr = x + (size_t)atom*F_;
  float a0 = 0.f, a1 = 0.f;
  int f0 = lane, f1 = lane + 64;
  for (int k = 0; k < 128; ++k){
    float xv = xr[k];
    a0 += xv*w_aw1[k*F_ + f0];
    a1 += xv*w_aw1[k*F_ + f1];
  }
  float h0 = sspf(a0 + b_aw1[f0]);
  float h1 = sspf(a1 + b_aw1[f1]);
  float s = h0*w_aw2[f0] + h1*w_aw2[f1];
  #pragma unroll
  for (int off = 32; off; off >>= 1) s += __shfl_down(s, off, 64);
  if (lane == 0) out[atom] = s + b_aw2[0];
}

extern "C" void kernel_launch(void* const* d_in, const int* in_sizes, int n_in,
                              void* d_out, int out_size, void* d_ws, size_t ws_size,
                              hipStream_t stream){
  const int*   z       = (const int*)d_in[0];
  const float* r       = (const float*)d_in[1];
  const float* emb     = (const float*)d_in[2];
  const float* w_in2f  = (const float*)d_in[3];
  const float* w_f1    = (const float*)d_in[4];
  const float* b_f1    = (const float*)d_in[5];
  const float* w_f2    = (const float*)d_in[6];
  const float* b_f2    = (const float*)d_in[7];
  const float* w_f2out = (const float*)d_in[8];
  const float* b_f2out = (const float*)d_in[9];
  const float* w_out   = (const float*)d_in[10];
  const float* b_out   = (const float*)d_in[11];
  const float* w_aw1   = (const float*)d_in[12];
  const float* b_aw1   = (const float*)d_in[13];
  const float* w_aw2   = (const float*)d_in[14];
  const float* b_aw2   = (const float*)d_in[15];

  char* ws = (char*)d_ws;
  float* x    = (float*)(ws);                        // 2,097,152 B
  float* f    = (float*)(ws + 2097152);              // 2,097,152 B
  u16*   w1t  = (u16*)(ws + 4194304);                //    81,920 B
  u16*   w2t  = (u16*)(ws + 4276224);                //    32,768 B
  u16*   wi2t = (u16*)(ws + 4308992);                //    32,768 B
  const size_t SMALL_END = 4341760;
  const size_t WB  = (size_t)NTILE*TILE_E*2;         // 2,359,296 B per batch elem
  const size_t YPB = (size_t)8*128*128*4;            // 524,288 B per batch elem

  int chunk_b = 1;
  if (ws_size > SMALL_END + WB + YPB){
    size_t cb = (ws_size - SMALL_END) / (WB + YPB);
    chunk_b = (cb > 32) ? 32 : (int)cb;
  }
  u16*   W  = (u16*)(ws + SMALL_END);
  float* yp = (float*)(ws + SMALL_END + (size_t)chunk_b*WB);

  k_setup<<<288, 256, 0, stream>>>(w_f1, w_f2, w_in2f, w1t, w2t, wi2t);
  k_embed<<<2048, 256, 0, stream>>>(z, emb, x);
  for (int b0 = 0; b0 < B_; b0 += chunk_b){
    int cb = (B_ - b0 < chunk_b) ? (B_ - b0) : chunk_b;
    k_filter<<<cb*NTILE*2, 256, 0, stream>>>(r, w1t, w2t, b_f1, b_f2, W, b0);
    for (int it = 0; it < 3; ++it){
      k_inlin<<<cb, 256, 0, stream>>>(x, wi2t, f, b0);
      k_cfconv<<<cb*NTILE, 256, 0, stream>>>(f, W, yp, b0);
      k_mlp<<<cb*8, 256, 0, stream>>>(yp, w_f2out, b_f2out, w_out, b_out, x, b0);
    }
  }
  k_readout<<<1024, 256, 0, stream>>>(x, w_aw1, b_aw1, w_aw2, b_aw2, (float*)d_out);
}